// Round 7
// baseline (900.514 us; speedup 1.0000x reference)
//
#include <hip/hip_runtime.h>
#include <hip/hip_bf16.h>
#include <math.h>

#define NN 100000
#define EE 1600000
#define HD 128
#define EPS_BN 1e-5f

typedef __attribute__((ext_vector_type(8))) short short8;   // 8 bf16 (4 VGPRs)
typedef __attribute__((ext_vector_type(4))) float f32x4;

__device__ inline float bf_hi(unsigned u) { return __uint_as_float(u & 0xffff0000u); }
__device__ inline float bf_lo(unsigned u) { return __uint_as_float(u << 16); }
__device__ inline unsigned pack_bf2(float x0, float x1) {
    __hip_bfloat16 a = __float2bfloat16(x0);
    __hip_bfloat16 b = __float2bfloat16(x1);
    unsigned short ua = *reinterpret_cast<unsigned short*>(&a);
    unsigned short ub = *reinterpret_cast<unsigned short*>(&b);
    return (unsigned)ua | ((unsigned)ub << 16);
}

// ---------------- prologue: conv_x + count_deg + prep_w (independent work, one launch) ----------------
__global__ __launch_bounds__(256) void prologue_k(const float* __restrict__ x, unsigned* __restrict__ xb,
                                                  const int* __restrict__ dst, int* __restrict__ deg,
                                                  const float* __restrict__ W0, const float* __restrict__ W1,
                                                  const float* __restrict__ W2, const float* __restrict__ W3,
                                                  const float* __restrict__ Wc,
                                                  __hip_bfloat16* __restrict__ Mb,
                                                  __hip_bfloat16* __restrict__ Wceb) {
    int t = blockIdx.x * 256 + threadIdx.x;    // grid is exactly EE = NN*HD/8 threads
    // x -> bf16 (one thread = 8 floats)
    {
        size_t base = (size_t)t * 8;
        float4 a = *(const float4*)&x[base];
        float4 b = *(const float4*)&x[base + 4];
        uint4 w;
        w.x = pack_bf2(a.x, a.y); w.y = pack_bf2(a.z, a.w);
        w.z = pack_bf2(b.x, b.y); w.w = pack_bf2(b.z, b.w);
        *(uint4*)&xb[(size_t)t * 4] = w;
    }
    // degree count
    atomicAdd(&deg[dst[t]], 1);
    // fused weights (only first 320 blocks)
    if (blockIdx.x < 320) {
        int part = blockIdx.x >> 6;                       // 0..4
        int idx = ((blockIdx.x & 63) << 8) + threadIdx.x; // 0..16383
        int o = idx >> 7, k = idx & 127;
        if (part < 4) {
            const float* W = (part == 0) ? W0 : (part == 1) ? W1 : (part == 2) ? W2 : W3;
            float s = 0.f;
            for (int j = 0; j < 128; ++j) s += Wc[o * 256 + j] * W[j * 128 + k];
            Mb[part * 16384 + idx] = __float2bfloat16(s);
        } else {
            Wceb[idx] = __float2bfloat16(Wc[o * 256 + 128 + k]);
        }
    }
}

// wave-scan allocation: one atomic per wave, all lanes active for shfl safety
__global__ __launch_bounds__(256) void alloc_off_k(const int* __restrict__ deg, int* __restrict__ off,
                                                   float* __restrict__ deg_inv, int* __restrict__ counter) {
    int v = blockIdx.x * 256 + threadIdx.x;
    int lane = threadIdx.x & 63;
    int d = (v < NN) ? deg[v] : 0;
    int scan = d;
#pragma unroll
    for (int s = 1; s < 64; s <<= 1) {
        int t = __shfl_up(scan, s);
        if (lane >= s) scan += t;
    }
    int wave_total = __shfl(scan, 63);
    int base = 0;
    if (lane == 63) base = atomicAdd(counter, wave_total);
    base = __shfl(base, 63);
    if (v < NN) {
        off[v] = base + scan - d;
        deg_inv[v] = 1.0f / (float)(d + 1);   // +1 self-loop
    }
}

__global__ __launch_bounds__(256) void fill_csr_k(const int* __restrict__ src, const int* __restrict__ dst,
                                                  const int* __restrict__ off, int* __restrict__ cursor,
                                                  int2* __restrict__ list) {
    int e = blockIdx.x * 256 + threadIdx.x;
    if (e < EE) {
        int v = dst[e];
        int p = atomicAdd(&cursor[v], 1);
        list[off[v] + p] = make_int2(e, src[e]);   // {edge id, src id} — one 8B store
    }
}

// ---------------- edge_attr aggregation: A[v] = sum ea[e], 4 chains/grp ----------------
__global__ __launch_bounds__(256) void agg_ea_k(const float* __restrict__ ea, const int* __restrict__ off,
                                                const int* __restrict__ deg, const int2* __restrict__ list,
                                                unsigned* __restrict__ A) {   // bf16x2 packed [N][64]
    int v = blockIdx.x * 4 + (threadIdx.x >> 6);
    int lane = threadIdx.x & 63;
    int grp = lane >> 5, lr = lane & 31;     // lr covers floats lr*4..+3 of a 512B row
    if (v >= NN) return;
    int o = off[v], d = deg[v];
    float a0 = 0.f, a1 = 0.f, a2 = 0.f, a3 = 0.f;
    float c0 = 0.f, c1 = 0.f, c2 = 0.f, c3 = 0.f;
    int j = grp;
    for (; j + 6 < d; j += 8) {
        int e0 = list[o + j].x;
        int e1 = list[o + j + 2].x;
        int e2 = list[o + j + 4].x;
        int e3 = list[o + j + 6].x;
        float4 r0 = *(const float4*)&ea[(size_t)e0 * HD + lr * 4];
        float4 r1 = *(const float4*)&ea[(size_t)e1 * HD + lr * 4];
        float4 r2 = *(const float4*)&ea[(size_t)e2 * HD + lr * 4];
        float4 r3 = *(const float4*)&ea[(size_t)e3 * HD + lr * 4];
        a0 += r0.x + r1.x; a1 += r0.y + r1.y; a2 += r0.z + r1.z; a3 += r0.w + r1.w;
        c0 += r2.x + r3.x; c1 += r2.y + r3.y; c2 += r2.z + r3.z; c3 += r2.w + r3.w;
    }
    for (; j + 2 < d; j += 4) {
        int e0 = list[o + j].x;
        int e1 = list[o + j + 2].x;
        float4 r0 = *(const float4*)&ea[(size_t)e0 * HD + lr * 4];
        float4 r1 = *(const float4*)&ea[(size_t)e1 * HD + lr * 4];
        a0 += r0.x + r1.x; a1 += r0.y + r1.y; a2 += r0.z + r1.z; a3 += r0.w + r1.w;
    }
    for (; j < d; j += 2) {
        int e = list[o + j].x;
        float4 r = *(const float4*)&ea[(size_t)e * HD + lr * 4];
        a0 += r.x; a1 += r.y; a2 += r.z; a3 += r.w;
    }
    a0 += c0; a1 += c1; a2 += c2; a3 += c3;
    a0 += __shfl_xor(a0, 32); a1 += __shfl_xor(a1, 32);
    a2 += __shfl_xor(a2, 32); a3 += __shfl_xor(a3, 32);
    if (grp == 0) {
        uint2 w;
        w.x = pack_bf2(a0, a1); w.y = pack_bf2(a2, a3);
        *(uint2*)&A[(size_t)v * 64 + lr * 2] = w;
    }
}

// ---------------- U GEMM: U = (A @ Wce^T)*deg_inv + bc  (bf16 out, row-major) ----------------
__global__ __launch_bounds__(256) void gemm_u_k(const __hip_bfloat16* __restrict__ Sb,
                                                const __hip_bfloat16* __restrict__ Bw,
                                                const float* __restrict__ deg_inv,
                                                const float* __restrict__ bias,
                                                __hip_bfloat16* __restrict__ out) {
    int wave = threadIdx.x >> 6, lane = threadIdx.x & 63;
    int r0 = blockIdx.x * 64 + wave * 16;
    int lr = lane & 15, lg = lane >> 4;

    f32x4 acc[8];
#pragma unroll
    for (int i = 0; i < 8; ++i) acc[i] = (f32x4){0.f, 0.f, 0.f, 0.f};

    int arow = r0 + lr;
    if (arow >= NN) arow = NN - 1;

#pragma unroll
    for (int kb = 0; kb < 4; ++kb) {
        int kofs = kb * 32 + lg * 8;
        short8 a = *(const short8*)(Sb + (size_t)arow * HD + kofs);
#pragma unroll
        for (int fr = 0; fr < 8; ++fr) {
            short8 b = *(const short8*)(Bw + (size_t)(fr * 16 + lr) * HD + kofs);
            acc[fr] = __builtin_amdgcn_mfma_f32_16x16x32_bf16(a, b, acc[fr], 0, 0, 0);
        }
    }
    float di[4];
#pragma unroll
    for (int j = 0; j < 4; ++j) {
        int grow = r0 + lg * 4 + j;
        di[j] = deg_inv[(grow < NN) ? grow : (NN - 1)];
    }
#pragma unroll
    for (int fr = 0; fr < 8; ++fr) {
        int col = fr * 16 + lr;
        float bs = bias[col];
#pragma unroll
        for (int j = 0; j < 4; ++j) {
            int grow = r0 + lg * 4 + j;
            if (grow >= NN) continue;
            out[(size_t)grow * HD + col] = __float2bfloat16(acc[fr][j] * di[j] + bs);
        }
    }
}

// ---------------- fused layer: gather-sum -> LDS -> MFMA -> epilogue ----------------
// MODE 1: tanh(BN(val*di + U + bias)) -> bf16 out ; MODE 2: val*di + U + bias -> f32 out
template <int MODE>
__global__ __launch_bounds__(256) void layer_k(const unsigned* __restrict__ tab,   // bf16x2 [N][64]
                                               const int2* __restrict__ list,
                                               const int* __restrict__ off, const int* __restrict__ deg,
                                               const float* __restrict__ deg_inv,
                                               const __hip_bfloat16* __restrict__ Bw,
                                               const __hip_bfloat16* __restrict__ Ub,
                                               const float* __restrict__ bias,
                                               const float* __restrict__ bng, const float* __restrict__ bnb,
                                               const float* __restrict__ bnm, const float* __restrict__ bnv,
                                               void* __restrict__ out) {
    __shared__ unsigned sA[64 * 68];    // 64 rows, stride 68 uints (pad for banks); 17.4 KB
    int wave = threadIdx.x >> 6, lane = threadIdx.x & 63;
    int grp = lane >> 4, lr = lane & 15;
    int nbase = blockIdx.x * 64 + wave * 16;

    // ---- gather phase: this wave's 16 rows (identical math to round-6 gather_sum_k) ----
    for (int i = 0; i < 16; ++i) {
        int v = nbase + i;
        if (v >= NN) v = NN - 1;                 // tail: duplicate work, stores guarded later
        int o = off[v], d = deg[v];
        float acc[8], acc2[8];
        {   // self row (count once: grp 0 only)
            uint4 r = *(const uint4*)&tab[(size_t)v * 64 + lr * 4];
            bool m = (grp == 0);
            acc[0] = m ? bf_lo(r.x) : 0.f; acc[1] = m ? bf_hi(r.x) : 0.f;
            acc[2] = m ? bf_lo(r.y) : 0.f; acc[3] = m ? bf_hi(r.y) : 0.f;
            acc[4] = m ? bf_lo(r.z) : 0.f; acc[5] = m ? bf_hi(r.z) : 0.f;
            acc[6] = m ? bf_lo(r.w) : 0.f; acc[7] = m ? bf_hi(r.w) : 0.f;
        }
#pragma unroll
        for (int q = 0; q < 8; ++q) acc2[q] = 0.f;
        int j = grp;
        for (; j + 12 < d; j += 16) {
            int s0 = list[o + j].y;
            int s1 = list[o + j + 4].y;
            int s2 = list[o + j + 8].y;
            int s3 = list[o + j + 12].y;
            uint4 r0 = *(const uint4*)&tab[(size_t)s0 * 64 + lr * 4];
            uint4 r1 = *(const uint4*)&tab[(size_t)s1 * 64 + lr * 4];
            uint4 r2 = *(const uint4*)&tab[(size_t)s2 * 64 + lr * 4];
            uint4 r3 = *(const uint4*)&tab[(size_t)s3 * 64 + lr * 4];
            acc[0] += bf_lo(r0.x) + bf_lo(r1.x); acc[1] += bf_hi(r0.x) + bf_hi(r1.x);
            acc[2] += bf_lo(r0.y) + bf_lo(r1.y); acc[3] += bf_hi(r0.y) + bf_hi(r1.y);
            acc[4] += bf_lo(r0.z) + bf_lo(r1.z); acc[5] += bf_hi(r0.z) + bf_hi(r1.z);
            acc[6] += bf_lo(r0.w) + bf_lo(r1.w); acc[7] += bf_hi(r0.w) + bf_hi(r1.w);
            acc2[0] += bf_lo(r2.x) + bf_lo(r3.x); acc2[1] += bf_hi(r2.x) + bf_hi(r3.x);
            acc2[2] += bf_lo(r2.y) + bf_lo(r3.y); acc2[3] += bf_hi(r2.y) + bf_hi(r3.y);
            acc2[4] += bf_lo(r2.z) + bf_lo(r3.z); acc2[5] += bf_hi(r2.z) + bf_hi(r3.z);
            acc2[6] += bf_lo(r2.w) + bf_lo(r3.w); acc2[7] += bf_hi(r2.w) + bf_hi(r3.w);
        }
        for (; j + 4 < d; j += 8) {
            int s0 = list[o + j].y;
            int s1 = list[o + j + 4].y;
            uint4 r0 = *(const uint4*)&tab[(size_t)s0 * 64 + lr * 4];
            uint4 r1 = *(const uint4*)&tab[(size_t)s1 * 64 + lr * 4];
            acc[0] += bf_lo(r0.x) + bf_lo(r1.x); acc[1] += bf_hi(r0.x) + bf_hi(r1.x);
            acc[2] += bf_lo(r0.y) + bf_lo(r1.y); acc[3] += bf_hi(r0.y) + bf_hi(r1.y);
            acc[4] += bf_lo(r0.z) + bf_lo(r1.z); acc[5] += bf_hi(r0.z) + bf_hi(r1.z);
            acc[6] += bf_lo(r0.w) + bf_lo(r1.w); acc[7] += bf_hi(r0.w) + bf_hi(r1.w);
        }
        for (; j < d; j += 4) {
            int s = list[o + j].y;
            uint4 r = *(const uint4*)&tab[(size_t)s * 64 + lr * 4];
            acc[0] += bf_lo(r.x); acc[1] += bf_hi(r.x);
            acc[2] += bf_lo(r.y); acc[3] += bf_hi(r.y);
            acc[4] += bf_lo(r.z); acc[5] += bf_hi(r.z);
            acc[6] += bf_lo(r.w); acc[7] += bf_hi(r.w);
        }
#pragma unroll
        for (int q = 0; q < 8; ++q) {
            acc[q] += acc2[q];
            acc[q] += __shfl_xor(acc[q], 16);
            acc[q] += __shfl_xor(acc[q], 32);
        }
        if (grp == 0) {
            uint4 w;
            w.x = pack_bf2(acc[0], acc[1]); w.y = pack_bf2(acc[2], acc[3]);
            w.z = pack_bf2(acc[4], acc[5]); w.w = pack_bf2(acc[6], acc[7]);
            *(uint4*)&sA[(wave * 16 + i) * 68 + lr * 4] = w;
        }
    }
    // No __syncthreads needed: each wave reads only the LDS rows it wrote.

    // ---- MFMA phase (wave's own 16 rows from LDS) ----
    f32x4 acc[8];
#pragma unroll
    for (int i = 0; i < 8; ++i) acc[i] = (f32x4){0.f, 0.f, 0.f, 0.f};
#pragma unroll
    for (int kb = 0; kb < 4; ++kb) {
        union { uint4 u; short8 s; } au;
        au.u = *(const uint4*)&sA[(wave * 16 + lr) * 68 + kb * 16 + grp * 4];
        int kofs = kb * 32 + grp * 8;
#pragma unroll
        for (int fr = 0; fr < 8; ++fr) {
            short8 b = *(const short8*)(Bw + (size_t)(fr * 16 + lr) * HD + kofs);
            acc[fr] = __builtin_amdgcn_mfma_f32_16x16x32_bf16(au.s, b, acc[fr], 0, 0, 0);
        }
    }

    float di[4];
#pragma unroll
    for (int j = 0; j < 4; ++j) {
        int grow = nbase + grp * 4 + j;
        di[j] = deg_inv[(grow < NN) ? grow : (NN - 1)];
    }
#pragma unroll
    for (int fr = 0; fr < 8; ++fr) {
        int col = fr * 16 + lr;
        float bs = bias[col];
        float me = 0.f, sc = 0.f, be = 0.f;
        if (MODE == 1) {
            me = bnm[col];
            sc = bng[col] * rsqrtf(bnv[col] + EPS_BN);
            be = bnb[col];
        }
#pragma unroll
        for (int j = 0; j < 4; ++j) {
            int grow = nbase + grp * 4 + j;
            if (grow >= NN) continue;
            float val = acc[fr][j] * di[j] + bs + __bfloat162float(Ub[(size_t)grow * HD + col]);
            if (MODE == 1) {
                val = tanhf((val - me) * sc + be);
                ((__hip_bfloat16*)out)[(size_t)grow * HD + col] = __float2bfloat16(val);
            } else {
                ((float*)out)[(size_t)grow * HD + col] = val;
            }
        }
    }
}

extern "C" void kernel_launch(void* const* d_in, const int* in_sizes, int n_in,
                              void* d_out, int out_size, void* d_ws, size_t ws_size,
                              hipStream_t stream) {
    const float* x   = (const float*)d_in[0];
    const int*   ei  = (const int*)d_in[1];
    const float* ea  = (const float*)d_in[2];
    const float* W0  = (const float*)d_in[3];
    const float* b0  = (const float*)d_in[4];
    const float* W1  = (const float*)d_in[5];
    const float* b1  = (const float*)d_in[6];
    const float* W2  = (const float*)d_in[7];
    const float* b2  = (const float*)d_in[8];
    const float* W3  = (const float*)d_in[9];
    const float* b3  = (const float*)d_in[10];
    const float* Wc  = (const float*)d_in[11];
    const float* bc  = (const float*)d_in[12];
    const float* bng = (const float*)d_in[13];
    const float* bnb = (const float*)d_in[14];
    const float* bnm = (const float*)d_in[15];
    const float* bnv = (const float*)d_in[16];

    const int* ei0 = ei;        // src
    const int* ei1 = ei + EE;   // dst

    char* ws = (char*)d_ws;
    int*   deg     = (int*)(ws + 0);                 // N*4
    int*   cursor  = (int*)(ws + 400000);            // N*4
    int*   counter = (int*)(ws + 800000);            // 4 (+pad)
    int*   off     = (int*)(ws + 800256);            // N*4
    float* deg_inv = (float*)(ws + 1200256);         // N*4 (+pad)
    __hip_bfloat16* Mb   = (__hip_bfloat16*)(ws + 1600512);   // 4*16384*2
    __hip_bfloat16* Wceb = (__hip_bfloat16*)(ws + 1731584);   // 16384*2
    int2*  list    = (int2*)(ws + 1764352);          // E*8 = 12.8 MB
    unsigned* A_b  = (unsigned*)(ws + 14564352);     // N*128 bf16 = 25.6 MB
    unsigned* U_b  = (unsigned*)(ws + 40164352);     // N*128 bf16
    unsigned* h_b  = (unsigned*)(ws + 65764352);     // N*128 bf16
    unsigned* x_b  = (unsigned*)(ws + 91364352);     // N*128 bf16 -> end ~117 MB
    (void)ws_size; (void)in_sizes; (void)n_in; (void)out_size;

    hipMemsetAsync(ws, 0, 800256, stream);  // deg, cursor, counter

    prologue_k<<<EE / 256, 256, 0, stream>>>(x, x_b, ei1, deg, W0, W1, W2, W3, Wc, Mb, Wceb);
    alloc_off_k<<<(NN + 255) / 256, 256, 0, stream>>>(deg, off, deg_inv, counter);
    fill_csr_k<<<(EE + 255) / 256, 256, 0, stream>>>(ei0, ei1, off, cursor, list);

    agg_ea_k<<<NN / 4, 256, 0, stream>>>(ea, off, deg, list, A_b);

    int gblocks = (NN + 63) / 64;
    gemm_u_k<<<gblocks, 256, 0, stream>>>((const __hip_bfloat16*)A_b, Wceb, deg_inv, bc,
                                          (__hip_bfloat16*)U_b);

    const float* biases[4] = {b0, b1, b2, b3};
    for (int layer = 0; layer < 4; ++layer) {
        const unsigned* tab = (layer == 0) ? x_b : h_b;
        if (layer < 3) {
            layer_k<1><<<gblocks, 256, 0, stream>>>(tab, list, off, deg, deg_inv,
                                                    Mb + layer * 16384, (const __hip_bfloat16*)U_b,
                                                    biases[layer], bng, bnb, bnm, bnv, (void*)h_b);
        } else {
            layer_k<2><<<gblocks, 256, 0, stream>>>(tab, list, off, deg, deg_inv,
                                                    Mb + layer * 16384, (const __hip_bfloat16*)U_b,
                                                    biases[layer], nullptr, nullptr, nullptr, nullptr,
                                                    d_out);
        }
    }
}

// Round 9
// 753.913 us; speedup vs baseline: 1.1945x; 1.1945x over previous
//
#include <hip/hip_runtime.h>
#include <hip/hip_bf16.h>
#include <math.h>

#define NN 100000
#define EE 1600000
#define HD 128
#define MAXDEG 128
#define EPS_BN 1e-5f

typedef __attribute__((ext_vector_type(8))) short short8;   // 8 bf16 (4 VGPRs)
typedef __attribute__((ext_vector_type(4))) float f32x4;

__device__ inline float bf_hi(unsigned u) { return __uint_as_float(u & 0xffff0000u); }
__device__ inline float bf_lo(unsigned u) { return __uint_as_float(u << 16); }
__device__ inline unsigned pack_bf2(float x0, float x1) {
    __hip_bfloat16 a = __float2bfloat16(x0);
    __hip_bfloat16 b = __float2bfloat16(x1);
    unsigned short ua = *reinterpret_cast<unsigned short*>(&a);
    unsigned short ub = *reinterpret_cast<unsigned short*>(&b);
    return (unsigned)ua | ((unsigned)ub << 16);
}

// ---------------- mega-prologue: conv_x + bucket CSR fill + prep_w, one launch ----------------
__global__ __launch_bounds__(256) void mega_k(const float* __restrict__ x, unsigned* __restrict__ xb,
                                              const int* __restrict__ src, const int* __restrict__ dst,
                                              int* __restrict__ cursor, int2* __restrict__ list,
                                              const float* __restrict__ W0, const float* __restrict__ W1,
                                              const float* __restrict__ W2, const float* __restrict__ W3,
                                              const float* __restrict__ Wc,
                                              __hip_bfloat16* __restrict__ Mb,
                                              __hip_bfloat16* __restrict__ Wceb) {
    int t = blockIdx.x * 256 + threadIdx.x;    // grid = EE/256 blocks exactly; t in [0, EE)
    // x -> bf16 (one thread = 8 floats; EE*8 == NN*HD)
    {
        size_t base = (size_t)t * 8;
        float4 a = *(const float4*)&x[base];
        float4 b = *(const float4*)&x[base + 4];
        uint4 w;
        w.x = pack_bf2(a.x, a.y); w.y = pack_bf2(a.z, a.w);
        w.z = pack_bf2(b.x, b.y); w.w = pack_bf2(b.z, b.w);
        *(uint4*)&xb[(size_t)t * 4] = w;
    }
    // bucket CSR fill: one edge per thread
    {
        int v = dst[t];
        int p = atomicAdd(&cursor[v], 1);
        if (p < MAXDEG) list[(size_t)v * MAXDEG + p] = make_int2(t, src[t]);
    }
    // fused weights (first 320 blocks)
    if (blockIdx.x < 320) {
        int part = blockIdx.x >> 6;                       // 0..4
        int idx = ((blockIdx.x & 63) << 8) + threadIdx.x; // 0..16383
        int o = idx >> 7, k = idx & 127;
        if (part < 4) {
            const float* W = (part == 0) ? W0 : (part == 1) ? W1 : (part == 2) ? W2 : W3;
            float s = 0.f;
            for (int j = 0; j < 128; ++j) s += Wc[o * 256 + j] * W[j * 128 + k];
            Mb[part * 16384 + idx] = __float2bfloat16(s);
        } else {
            Wceb[idx] = __float2bfloat16(Wc[o * 256 + 128 + k]);
        }
    }
}

// ---------------- edge_attr aggregation: A[v] = sum ea[e], 4 chains/grp ----------------
__global__ __launch_bounds__(256) void agg_ea_k(const float* __restrict__ ea,
                                                const int* __restrict__ deg, const int2* __restrict__ list,
                                                unsigned* __restrict__ A) {   // bf16x2 packed [N][64]
    int v = blockIdx.x * 4 + (threadIdx.x >> 6);
    int lane = threadIdx.x & 63;
    int grp = lane >> 5, lr = lane & 31;     // lr covers floats lr*4..+3 of a 512B row
    if (v >= NN) return;
    size_t o = (size_t)v * MAXDEG;
    int d = deg[v];
    float a0 = 0.f, a1 = 0.f, a2 = 0.f, a3 = 0.f;
    float c0 = 0.f, c1 = 0.f, c2 = 0.f, c3 = 0.f;
    int j = grp;
    for (; j + 6 < d; j += 8) {
        int e0 = list[o + j].x;
        int e1 = list[o + j + 2].x;
        int e2 = list[o + j + 4].x;
        int e3 = list[o + j + 6].x;
        float4 r0 = *(const float4*)&ea[(size_t)e0 * HD + lr * 4];
        float4 r1 = *(const float4*)&ea[(size_t)e1 * HD + lr * 4];
        float4 r2 = *(const float4*)&ea[(size_t)e2 * HD + lr * 4];
        float4 r3 = *(const float4*)&ea[(size_t)e3 * HD + lr * 4];
        a0 += r0.x + r1.x; a1 += r0.y + r1.y; a2 += r0.z + r1.z; a3 += r0.w + r1.w;
        c0 += r2.x + r3.x; c1 += r2.y + r3.y; c2 += r2.z + r3.z; c3 += r2.w + r3.w;
    }
    for (; j + 2 < d; j += 4) {
        int e0 = list[o + j].x;
        int e1 = list[o + j + 2].x;
        float4 r0 = *(const float4*)&ea[(size_t)e0 * HD + lr * 4];
        float4 r1 = *(const float4*)&ea[(size_t)e1 * HD + lr * 4];
        a0 += r0.x + r1.x; a1 += r0.y + r1.y; a2 += r0.z + r1.z; a3 += r0.w + r1.w;
    }
    for (; j < d; j += 2) {
        int e = list[o + j].x;
        float4 r = *(const float4*)&ea[(size_t)e * HD + lr * 4];
        a0 += r.x; a1 += r.y; a2 += r.z; a3 += r.w;
    }
    a0 += c0; a1 += c1; a2 += c2; a3 += c3;
    a0 += __shfl_xor(a0, 32); a1 += __shfl_xor(a1, 32);
    a2 += __shfl_xor(a2, 32); a3 += __shfl_xor(a3, 32);
    if (grp == 0) {
        uint2 w;
        w.x = pack_bf2(a0, a1); w.y = pack_bf2(a2, a3);
        *(uint2*)&A[(size_t)v * 64 + lr * 2] = w;
    }
}

// ---------------- neighbor sum S[v] = tab[v] + sum tab[src], 4 chains/grp ----------------
__global__ __launch_bounds__(256) void gather_sum_k(const unsigned* __restrict__ tab,  // bf16x2 [N][64]
                                                    const int* __restrict__ deg, const int2* __restrict__ list,
                                                    unsigned* __restrict__ S) {
    int v = blockIdx.x * 4 + (threadIdx.x >> 6);
    int lane = threadIdx.x & 63;
    int grp = lane >> 4, lr = lane & 15;     // lr covers uints lr*4..+3 (channels lr*8..+7)
    if (v >= NN) return;
    size_t o = (size_t)v * MAXDEG;
    int d = deg[v];
    float acc[8], acc2[8];
    {   // self row (count once: grp 0 only)
        uint4 r = *(const uint4*)&tab[(size_t)v * 64 + lr * 4];
        bool m = (grp == 0);
        acc[0] = m ? bf_lo(r.x) : 0.f; acc[1] = m ? bf_hi(r.x) : 0.f;
        acc[2] = m ? bf_lo(r.y) : 0.f; acc[3] = m ? bf_hi(r.y) : 0.f;
        acc[4] = m ? bf_lo(r.z) : 0.f; acc[5] = m ? bf_hi(r.z) : 0.f;
        acc[6] = m ? bf_lo(r.w) : 0.f; acc[7] = m ? bf_hi(r.w) : 0.f;
    }
#pragma unroll
    for (int i = 0; i < 8; ++i) acc2[i] = 0.f;
    int j = grp;
    for (; j + 12 < d; j += 16) {
        int s0 = list[o + j].y;
        int s1 = list[o + j + 4].y;
        int s2 = list[o + j + 8].y;
        int s3 = list[o + j + 12].y;
        uint4 r0 = *(const uint4*)&tab[(size_t)s0 * 64 + lr * 4];
        uint4 r1 = *(const uint4*)&tab[(size_t)s1 * 64 + lr * 4];
        uint4 r2 = *(const uint4*)&tab[(size_t)s2 * 64 + lr * 4];
        uint4 r3 = *(const uint4*)&tab[(size_t)s3 * 64 + lr * 4];
        acc[0] += bf_lo(r0.x) + bf_lo(r1.x); acc[1] += bf_hi(r0.x) + bf_hi(r1.x);
        acc[2] += bf_lo(r0.y) + bf_lo(r1.y); acc[3] += bf_hi(r0.y) + bf_hi(r1.y);
        acc[4] += bf_lo(r0.z) + bf_lo(r1.z); acc[5] += bf_hi(r0.z) + bf_hi(r1.z);
        acc[6] += bf_lo(r0.w) + bf_lo(r1.w); acc[7] += bf_hi(r0.w) + bf_hi(r1.w);
        acc2[0] += bf_lo(r2.x) + bf_lo(r3.x); acc2[1] += bf_hi(r2.x) + bf_hi(r3.x);
        acc2[2] += bf_lo(r2.y) + bf_lo(r3.y); acc2[3] += bf_hi(r2.y) + bf_hi(r3.y);
        acc2[4] += bf_lo(r2.z) + bf_lo(r3.z); acc2[5] += bf_hi(r2.z) + bf_hi(r3.z);
        acc2[6] += bf_lo(r2.w) + bf_lo(r3.w); acc2[7] += bf_hi(r2.w) + bf_hi(r3.w);
    }
    for (; j + 4 < d; j += 8) {
        int s0 = list[o + j].y;
        int s1 = list[o + j + 4].y;
        uint4 r0 = *(const uint4*)&tab[(size_t)s0 * 64 + lr * 4];
        uint4 r1 = *(const uint4*)&tab[(size_t)s1 * 64 + lr * 4];
        acc[0] += bf_lo(r0.x) + bf_lo(r1.x); acc[1] += bf_hi(r0.x) + bf_hi(r1.x);
        acc[2] += bf_lo(r0.y) + bf_lo(r1.y); acc[3] += bf_hi(r0.y) + bf_hi(r1.y);
        acc[4] += bf_lo(r0.z) + bf_lo(r1.z); acc[5] += bf_hi(r0.z) + bf_hi(r1.z);
        acc[6] += bf_lo(r0.w) + bf_lo(r1.w); acc[7] += bf_hi(r0.w) + bf_hi(r1.w);
    }
    for (; j < d; j += 4) {
        int s = list[o + j].y;
        uint4 r = *(const uint4*)&tab[(size_t)s * 64 + lr * 4];
        acc[0] += bf_lo(r.x); acc[1] += bf_hi(r.x);
        acc[2] += bf_lo(r.y); acc[3] += bf_hi(r.y);
        acc[4] += bf_lo(r.z); acc[5] += bf_hi(r.z);
        acc[6] += bf_lo(r.w); acc[7] += bf_hi(r.w);
    }
#pragma unroll
    for (int i = 0; i < 8; ++i) {
        acc[i] += acc2[i];
        acc[i] += __shfl_xor(acc[i], 16);
        acc[i] += __shfl_xor(acc[i], 32);
    }
    if (grp == 0) {
        uint4 w;
        w.x = pack_bf2(acc[0], acc[1]); w.y = pack_bf2(acc[2], acc[3]);
        w.z = pack_bf2(acc[4], acc[5]); w.w = pack_bf2(acc[6], acc[7]);
        *(uint4*)&S[(size_t)v * 64 + lr * 4] = w;
    }
}

// ---------------- MFMA GEMM with fused epilogue ----------------
//   MODE 0: val*di + bias               -> bf16 out   (U build)
//   MODE 1: tanh(BN(val*di + U + bias)) -> bf16 out   (mid layer)
//   MODE 2: val*di + U + bias           -> f32 out    (last layer)
template <int MODE>
__global__ __launch_bounds__(256) void gemm_epi_k(const __hip_bfloat16* __restrict__ Sb,
                                                  const __hip_bfloat16* __restrict__ Bw,
                                                  const __hip_bfloat16* __restrict__ Ub,
                                                  const int* __restrict__ deg,
                                                  const float* __restrict__ bias,
                                                  const float* __restrict__ bng, const float* __restrict__ bnb,
                                                  const float* __restrict__ bnm, const float* __restrict__ bnv,
                                                  void* __restrict__ out) {
    int wave = threadIdx.x >> 6, lane = threadIdx.x & 63;
    int r0 = blockIdx.x * 64 + wave * 16;
    int lr = lane & 15, lg = lane >> 4;

    f32x4 acc[8];
#pragma unroll
    for (int i = 0; i < 8; ++i) acc[i] = (f32x4){0.f, 0.f, 0.f, 0.f};

    int arow = r0 + lr;
    if (arow >= NN) arow = NN - 1;   // clamp (stores guarded)

#pragma unroll
    for (int kb = 0; kb < 4; ++kb) {
        int kofs = kb * 32 + lg * 8;
        short8 a = *(const short8*)(Sb + (size_t)arow * HD + kofs);
#pragma unroll
        for (int fr = 0; fr < 8; ++fr) {
            short8 b = *(const short8*)(Bw + (size_t)(fr * 16 + lr) * HD + kofs);
            acc[fr] = __builtin_amdgcn_mfma_f32_16x16x32_bf16(a, b, acc[fr], 0, 0, 0);
        }
    }

    float di[4];
#pragma unroll
    for (int j = 0; j < 4; ++j) {
        int grow = r0 + lg * 4 + j;
        int d = deg[(grow < NN) ? grow : (NN - 1)];
        di[j] = 1.0f / (float)(d + 1);
    }
#pragma unroll
    for (int fr = 0; fr < 8; ++fr) {
        int col = fr * 16 + lr;
        float bs = bias[col];
        float me = 0.f, sc = 0.f, be = 0.f;
        if (MODE == 1) {
            me = bnm[col];
            sc = bng[col] * rsqrtf(bnv[col] + EPS_BN);
            be = bnb[col];
        }
#pragma unroll
        for (int j = 0; j < 4; ++j) {
            int grow = r0 + lg * 4 + j;
            if (grow >= NN) continue;
            float val = acc[fr][j] * di[j] + bs;
            if (MODE != 0) val += __bfloat162float(Ub[(size_t)grow * HD + col]);
            if (MODE == 1) {
                val = tanhf((val - me) * sc + be);
            }
            if (MODE == 2) {
                ((float*)out)[(size_t)grow * HD + col] = val;
            } else {
                ((__hip_bfloat16*)out)[(size_t)grow * HD + col] = __float2bfloat16(val);
            }
        }
    }
}

extern "C" void kernel_launch(void* const* d_in, const int* in_sizes, int n_in,
                              void* d_out, int out_size, void* d_ws, size_t ws_size,
                              hipStream_t stream) {
    const float* x   = (const float*)d_in[0];
    const int*   ei  = (const int*)d_in[1];
    const float* ea  = (const float*)d_in[2];
    const float* W0  = (const float*)d_in[3];
    const float* b0  = (const float*)d_in[4];
    const float* W1  = (const float*)d_in[5];
    const float* b1  = (const float*)d_in[6];
    const float* W2  = (const float*)d_in[7];
    const float* b2  = (const float*)d_in[8];
    const float* W3  = (const float*)d_in[9];
    const float* b3  = (const float*)d_in[10];
    const float* Wc  = (const float*)d_in[11];
    const float* bc  = (const float*)d_in[12];
    const float* bng = (const float*)d_in[13];
    const float* bnb = (const float*)d_in[14];
    const float* bnm = (const float*)d_in[15];
    const float* bnv = (const float*)d_in[16];

    const int* ei0 = ei;        // src
    const int* ei1 = ei + EE;   // dst

    char* ws = (char*)d_ws;
    // NOTE (round-8 bug): node tables are N*128 bf16 = 25,600,000 B each; they were
    // spaced 12.8 MB apart -> overlap -> absmax 15. Now spaced 25.6 MB apart.
    int*   cursor  = (int*)(ws + 0);                 // N*4 = 400000 (doubles as deg)
    __hip_bfloat16* Mb   = (__hip_bfloat16*)(ws + 400128);    // 4*16384*2 = 131072
    __hip_bfloat16* Wceb = (__hip_bfloat16*)(ws + 531200);    // 16384*2 = 32768
    int2*  list    = (int2*)(ws + 564224);           // N*128*8 = 102,400,000 -> ends 102,964,224
    unsigned* A_b  = (unsigned*)(ws + 102964224);    // 25.6 MB
    unsigned* U_b  = (unsigned*)(ws + 128564224);    // 25.6 MB
    unsigned* S_b  = (unsigned*)(ws + 154164224);    // 25.6 MB
    unsigned* h_b  = (unsigned*)(ws + 179764224);    // 25.6 MB
    unsigned* x_b  = (unsigned*)(ws + 205364224);    // 25.6 MB -> end 230,964,224 (~231 MB)
    (void)ws_size; (void)in_sizes; (void)n_in; (void)out_size;

    hipMemsetAsync(cursor, 0, 400000, stream);  // degree counters only

    mega_k<<<EE / 256, 256, 0, stream>>>(x, x_b, ei0, ei1, cursor, list,
                                         W0, W1, W2, W3, Wc, Mb, Wceb);

    agg_ea_k<<<NN / 4, 256, 0, stream>>>(ea, cursor, list, A_b);

    int gblocks = (NN + 63) / 64;
    // U = (A @ Wce^T) * deg_inv + bc
    gemm_epi_k<0><<<gblocks, 256, 0, stream>>>((const __hip_bfloat16*)A_b, Wceb, nullptr,
                                               cursor, bc, nullptr, nullptr, nullptr, nullptr,
                                               (void*)U_b);

    const float* biases[4] = {b0, b1, b2, b3};
    for (int layer = 0; layer < 4; ++layer) {
        const unsigned* tab = (layer == 0) ? x_b : h_b;
        gather_sum_k<<<NN / 4, 256, 0, stream>>>(tab, cursor, list, S_b);
        if (layer < 3) {
            gemm_epi_k<1><<<gblocks, 256, 0, stream>>>((const __hip_bfloat16*)S_b, Mb + layer * 16384,
                                                       (const __hip_bfloat16*)U_b, cursor, biases[layer],
                                                       bng, bnb, bnm, bnv, (void*)h_b);
        } else {
            gemm_epi_k<2><<<gblocks, 256, 0, stream>>>((const __hip_bfloat16*)S_b, Mb + layer * 16384,
                                                       (const __hip_bfloat16*)U_b, cursor, biases[layer],
                                                       nullptr, nullptr, nullptr, nullptr, d_out);
        }
    }
}